// Round 6
// baseline (172.519 us; speedup 1.0000x reference)
//
#include <hip/hip_runtime.h>
#include <hip/hip_fp16.h>

// Problem constants (from reference):
//   x:    (B=2, C=8, F=80, N=128, N=128) fp32
//   quad: (H=512, W=1024) int32 in [0, F)
//   uv:   (H, W, 2) fp32 in [0, N-1)
//   out:  (B, C, H, W) fp32
#define BC   16                 // B*C
#define FD   80
#define ND   128
#define NN   (ND * ND)          // 16384
#define HW   (512 * 1024)       // 524288 = 2^19
#define HW_SHIFT 19

// Two u-parity copies of the fp16 channel-packed texture.
#define COPY_HALVES ((size_t)FD * NN * BC)                 // 20,971,520 halves
#define Z_BYTES     (2 * COPY_HALVES * sizeof(__half))    // 83,886,080 B

// ---------------------------------------------------------------------------
// Kernel 1 (repack v3, no LDS): one thread per texel (f, v, u).
//   - 16 coalesced b32 loads (lane = u -> 256 B per wave instr), 16-deep MLP
//   - pack 16 halves in registers
//   - copy0: slot u  (texel u at slot u)       -> pairs (0,1),(2,3),...
//   - copy1: slot u-1 (texel u at slot u-1)    -> pairs (1,2),(3,4),...
// Every v-row pair (u0, u0+1) is one 64B-aligned line in one of the copies.
// ---------------------------------------------------------------------------
__global__ __launch_bounds__(256)
void repack_kernel(const float* __restrict__ x, __half* __restrict__ z)
{
    const int gid = blockIdx.x * 256 + threadIdx.x;   // 0 .. FD*ND*ND-1
    const int u   = gid & (ND - 1);
    const int fv  = gid >> 7;                         // (f, v) row id

    const size_t texel = (size_t)fv * ND + u;         // index within one channel

    float g[BC];
#pragma unroll
    for (int c = 0; c < BC; ++c)
        g[c] = x[(size_t)c * ((size_t)FD * NN) + texel];

    unsigned hp[8];
#pragma unroll
    for (int j = 0; j < 8; ++j) {
        const __half2 h = __floats2half2_rn(g[2 * j], g[2 * j + 1]);
        hp[j] = *(const unsigned*)&h;
    }
    const uint4 h0 = make_uint4(hp[0], hp[1], hp[2], hp[3]);
    const uint4 h1 = make_uint4(hp[4], hp[5], hp[6], hp[7]);

    // copy 0: slot u
    __half* r0 = z + (size_t)fv * (ND * BC) + (size_t)u * BC;
    *(uint4*)(r0)     = h0;
    *(uint4*)(r0 + 8) = h1;

    // copy 1: slot u-1 (slot 127 of each row never read; u==0 skipped)
    if (u > 0) {
        __half* r1 = z + COPY_HALVES + (size_t)fv * (ND * BC) + (size_t)(u - 1) * BC;
        *(uint4*)(r1)     = h0;
        *(uint4*)(r1 + 8) = h1;
    }
}

// ---------------------------------------------------------------------------
// Kernel 2 (gather): one thread per pixel, all 16 channels.
// Pick copy p = u0&1; pair base slot = u0 - p (even) -> each v-row read is
// one fully-consumed 64B-aligned line. Exactly 2 lines per pixel.
// ---------------------------------------------------------------------------
__device__ inline void acc8(float* o, uint4 t, float w)
{
    const unsigned* p = (const unsigned*)&t;
#pragma unroll
    for (int j = 0; j < 4; ++j) {
        const float2 fp = __half22float2(*(const __half2*)&p[j]);
        o[2 * j + 0] += fp.x * w;
        o[2 * j + 1] += fp.y * w;
    }
}

__global__ __launch_bounds__(256)
void gather_kernel(const __half* __restrict__ z,
                   const int*    __restrict__ quad,
                   const float2* __restrict__ uv2,
                   float* __restrict__ out)
{
    const int pix = blockIdx.x * 256 + threadIdx.x;

    const float2 t = uv2[pix];
    const int    f = quad[pix];

    const float u = t.x;
    const float v = t.y;

    int u0 = (int)floorf(u);
    int v0 = (int)floorf(v);
    u0 = min(max(u0, 0), ND - 2);
    v0 = min(max(v0, 0), ND - 2);

    const int p    = u0 & 1;            // which copy
    const int slot = u0 - p;            // even slot: 64B-aligned pair base

    // base in halves: (((p*FD + f)*ND + v0)*ND + slot) * BC
    const size_t base = ((((size_t)p * FD + f) * ND + v0) * ND + slot) * BC;
    const uint4* r0 = (const uint4*)(z + base);                    // row v0
    const uint4* r1 = (const uint4*)(z + base + (size_t)ND * BC);  // row v0+1

    const uint4 a0 = r0[0], a1 = r0[1];   // (v0,  u0)   ch0-7, ch8-15
    const uint4 b0 = r0[2], b1 = r0[3];   // (v0,  u0+1)
    const uint4 c0 = r1[0], c1 = r1[1];   // (v0+1,u0)
    const uint4 d0 = r1[2], d1 = r1[3];   // (v0+1,u0+1)

    const float du = u - (float)u0;
    const float dv = v - (float)v0;
    const float w00 = (1.0f - du) * (1.0f - dv);
    const float w01 = du * (1.0f - dv);
    const float w10 = (1.0f - du) * dv;
    const float w11 = du * dv;

    float o[BC];
#pragma unroll
    for (int c = 0; c < BC; ++c) o[c] = 0.0f;

    acc8(o,     a0, w00); acc8(o + 8, a1, w00);
    acc8(o,     b0, w01); acc8(o + 8, b1, w01);
    acc8(o,     c0, w10); acc8(o + 8, c1, w10);
    acc8(o,     d0, w11); acc8(o + 8, d1, w11);

#pragma unroll
    for (int c = 0; c < BC; ++c)
        __builtin_nontemporal_store(o[c], &out[(size_t)c * HW + pix]);
}

// ---------------------------------------------------------------------------
// Fallback: used only if ws_size can't hold the replicated texture.
// ---------------------------------------------------------------------------
__global__ __launch_bounds__(256)
void resample_fallback_kernel(const float* __restrict__ x,
                              const int*   __restrict__ quad,
                              const float2* __restrict__ uv2,
                              float* __restrict__ out)
{
    const int gid = blockIdx.x * 256 + threadIdx.x;
    const int pix = gid & (HW - 1);
    const int bc  = gid >> HW_SHIFT;

    const float2 t = uv2[pix];
    const int    f = quad[pix];

    const float u = t.x;
    const float v = t.y;

    int u0 = (int)floorf(u);
    int v0 = (int)floorf(v);
    u0 = min(max(u0, 0), ND - 2);
    v0 = min(max(v0, 0), ND - 2);

    const float du = u - (float)u0;
    const float dv = v - (float)v0;

    const float w00 = (1.0f - du) * (1.0f - dv);
    const float w01 = du * (1.0f - dv);
    const float w10 = (1.0f - du) * dv;
    const float w11 = du * dv;

    const float* p = x + ((size_t)bc * FD + (size_t)f) * NN + v0 * ND + u0;
    out[gid] = p[0] * w00 + p[1] * w01 + p[ND] * w10 + p[ND + 1] * w11;
}

extern "C" void kernel_launch(void* const* d_in, const int* in_sizes, int n_in,
                              void* d_out, int out_size, void* d_ws, size_t ws_size,
                              hipStream_t stream)
{
    const float*  x    = (const float*)d_in[0];
    const int*    quad = (const int*)d_in[1];
    const float2* uv2  = (const float2*)d_in[2];
    float*        out  = (float*)d_out;

    if (ws_size >= Z_BYTES) {
        __half* z = (__half*)d_ws;
        const int texels = FD * ND * ND;                       // 1,310,720
        repack_kernel<<<texels / 256, 256, 0, stream>>>(x, z); // 5120 blocks
        gather_kernel<<<HW / 256, 256, 0, stream>>>(z, quad, uv2, out); // 2048 blocks
    } else {
        const int total = BC * HW;
        resample_fallback_kernel<<<total / 256, 256, 0, stream>>>(x, quad, uv2, out);
    }
}